// Round 1
// baseline (9550.370 us; speedup 1.0000x reference)
//
#include <hip/hip_runtime.h>
#include <hip/hip_bf16.h>

typedef unsigned int  u32;
typedef unsigned short u16;
typedef float f32x4 __attribute__((ext_vector_type(4)));
typedef short bf16x8 __attribute__((ext_vector_type(8)));

#define AGENT __HIP_MEMORY_SCOPE_AGENT
__device__ inline float aloadf(const float* p){ return __hip_atomic_load(p, __ATOMIC_RELAXED, AGENT); }
__device__ inline void  astoref(float* p, float v){ __hip_atomic_store(p, v, __ATOMIC_RELAXED, AGENT); }
__device__ inline int   aloadi_acq(const int* p){ return __hip_atomic_load(p, __ATOMIC_ACQUIRE, AGENT); }
__device__ inline void  astorei_rel(int* p, int v){ __hip_atomic_store(p, v, __ATOMIC_RELEASE, AGENT); }

__device__ __host__ inline u16 f2bf(float f){
  u32 u = __builtin_bit_cast(u32, f);
  u += 0x7fffu + ((u >> 16) & 1u);
  return (u16)(u >> 16);
}
__device__ inline float bflo(u32 a){ return __uint_as_float(a << 16); }
__device__ inline float bfhi(u32 a){ return __uint_as_float(a & 0xffff0000u); }
__device__ inline float sigm(float x){ return 1.f/(1.f + expf(-x)); }

__device__ inline float wred_sum(float v){
#pragma unroll
  for (int m = 32; m >= 1; m >>= 1) v += __shfl_xor(v, m, 64);
  return v;
}
__device__ inline float bred_sum(float v, float* red, int tid){
  v = wred_sum(v);
  if ((tid & 63) == 0) red[tid >> 6] = v;
  __syncthreads();
  float r = red[0] + red[1] + red[2] + red[3];
  __syncthreads();
  return r;
}
__device__ inline float bred_max(float v, float* red, int tid){
#pragma unroll
  for (int m = 32; m >= 1; m >>= 1) v = fmaxf(v, __shfl_xor(v, m, 64));
  if ((tid & 63) == 0) red[tid >> 6] = v;
  __syncthreads();
  float r = fmaxf(fmaxf(red[0], red[1]), fmaxf(red[2], red[3]));
  __syncthreads();
  return r;
}

// ---------------------------------------------------------------- fp32 -> bf16
__global__ void k_cvt(const float* __restrict__ s, u16* __restrict__ d, int n4){
  int i = blockIdx.x * 256 + threadIdx.x;
  int stride = gridDim.x * 256;
  const float4* s4 = (const float4*)s;
  for (; i < n4; i += stride){
    float4 v = s4[i];
    ushort4 o;
    o.x = f2bf(v.x); o.y = f2bf(v.y); o.z = f2bf(v.z); o.w = f2bf(v.w);
    ((ushort4*)d)[i] = o;
  }
}

// ---------------------------------------------------------------- img xp GEMM
// C[M=1024][N=2048] = A[1024][2048]bf16 . B[N][K]bf16^T + bias, out fp32
__global__ __launch_bounds__(256, 1) void k_gemm_xp(
    const u16* __restrict__ A,
    const u16* __restrict__ B0, const u16* __restrict__ B1,
    const float* __restrict__ bias0, const float* __restrict__ bias1,
    float* __restrict__ C0, float* __restrict__ C1)
{
  const int K = 2048, N = 2048;
  const int bx = blockIdx.x, by = blockIdx.y, z = blockIdx.z;
  const u16* B = z ? B1 : B0;
  const float* bias = z ? bias1 : bias0;
  float* C = z ? C1 : C0;
  const int tid = threadIdx.x;
  const int lane = tid & 63, wv = tid >> 6;
  const int m0 = by * 128, n0 = bx * 128;
  const int wm = (wv >> 1) * 64, wn = (wv & 1) * 64;

  __shared__ __align__(16) u16 lA[128 * 32];
  __shared__ __align__(16) u16 lB[128 * 32];

  f32x4 acc[4][4];
#pragma unroll
  for (int i = 0; i < 4; ++i)
#pragma unroll
    for (int j = 0; j < 4; ++j) acc[i][j] = (f32x4){0.f, 0.f, 0.f, 0.f};

  const int lrow = tid >> 2;
  const int lcol = (tid & 3) * 8;
  const u16* aBase = A + (size_t)(m0 + lrow) * K + lcol;
  const u16* bBase = B + (size_t)(n0 + lrow) * K + lcol;

  for (int kk = 0; kk < K; kk += 32){
#pragma unroll
    for (int io = 0; io < 2; ++io){
      __builtin_amdgcn_global_load_lds(
        (const __attribute__((address_space(1))) void*)(aBase + (size_t)io * 64 * K + kk),
        (__attribute__((address_space(3))) void*)((char*)lA + wv * 1024 + io * 4096), 16, 0, 0);
      __builtin_amdgcn_global_load_lds(
        (const __attribute__((address_space(1))) void*)(bBase + (size_t)io * 64 * K + kk),
        (__attribute__((address_space(3))) void*)((char*)lB + wv * 1024 + io * 4096), 16, 0, 0);
    }
    asm volatile("s_waitcnt vmcnt(0)");
    __syncthreads();

    bf16x8 af[4], bfr[4];
#pragma unroll
    for (int i = 0; i < 4; ++i){
      af[i]  = *(const bf16x8*)&lA[(wm + i * 16 + (lane & 15)) * 32 + (lane >> 4) * 8];
      bfr[i] = *(const bf16x8*)&lB[(wn + i * 16 + (lane & 15)) * 32 + (lane >> 4) * 8];
    }
#pragma unroll
    for (int i = 0; i < 4; ++i)
#pragma unroll
      for (int j = 0; j < 4; ++j)
        acc[i][j] = __builtin_amdgcn_mfma_f32_16x16x32_bf16(af[i], bfr[j], acc[i][j], 0, 0, 0);
    __syncthreads();
  }

  const int rbase = (lane >> 4) * 4;
  const int ccol = lane & 15;
#pragma unroll
  for (int i = 0; i < 4; ++i)
#pragma unroll
    for (int j = 0; j < 4; ++j){
      int col = n0 + wn + j * 16 + ccol;
      float bv = bias[col];
#pragma unroll
      for (int r2 = 0; r2 < 4; ++r2){
        int row = m0 + wm + i * 16 + rbase + r2;
        C[(size_t)row * N + col] = acc[i][j][r2] + bv;
      }
    }
}

// ---------------------------------------------------------------- q xp (small fp32 GEMM)
__global__ __launch_bounds__(256, 1) void k_qxp(
    const float* __restrict__ qf,
    const float* __restrict__ W0, const float* __restrict__ W1,
    const float* __restrict__ bb0, const float* __restrict__ bb1,
    float* __restrict__ o0, float* __restrict__ o1)
{
  const int bx = blockIdx.x;       // n-chunk of 64
  const int z = blockIdx.y;
  const float* W = z ? W1 : W0;
  const float* bb = z ? bb1 : bb0;
  float* o = z ? o1 : o0;
  const int tid = threadIdx.x;
  __shared__ float xs[32 * 301];
  __shared__ float Ws[64 * 301];
  for (int idx = tid; idx < 32 * 300; idx += 256){
    int m = idx / 300, k = idx - m * 300;
    xs[m * 301 + k] = qf[idx];
  }
  for (int idx = tid; idx < 64 * 300; idx += 256){
    int j = idx / 300, k = idx - j * 300;
    Ws[j * 301 + k] = W[(size_t)(bx * 64 + j) * 300 + k];
  }
  __syncthreads();
  for (int i = 0; i < 8; ++i){
    int idx = tid + i * 256;
    int nl = idx >> 5, m = idx & 31;
    float s = 0;
    for (int k = 0; k < 300; ++k) s = fmaf(xs[m * 301 + k], Ws[nl * 301 + k], s);
    o[(size_t)m * 2048 + bx * 64 + nl] = s + bb[bx * 64 + nl];
  }
}

// ---------------------------------------------------------------- LSTM scans (4 directions)
// 32 blocks per direction. Block owns 16 h-elems => 64 gate rows in LDS (bf16).
__global__ __launch_bounds__(256, 1) void k_scan(
    const float* __restrict__ WhA, const float* __restrict__ WhB,
    const float* __restrict__ WhC, const float* __restrict__ WhD,
    const float* __restrict__ xpA, const float* __restrict__ xpB,
    const float* __restrict__ xpC, const float* __restrict__ xpD,
    float* __restrict__ emb, float* __restrict__ embT,
    float* __restrict__ qemb, float* __restrict__ qembT,
    float* hglob, int* stamps)
{
  const int tid = threadIdx.x;
  const int dir = blockIdx.x >> 5;
  const int sub = blockIdx.x & 31;
  const float* Wh = dir == 0 ? WhA : dir == 1 ? WhB : dir == 2 ? WhC : WhD;
  const float* xp = dir == 0 ? xpA : dir == 1 ? xpB : dir == 2 ? xpC : xpD;
  const int L = (dir < 2) ? 1024 : 32;
  const int rev = dir & 1;
  float* oe  = (dir < 2) ? emb  : qemb;
  float* oeT = (dir < 2) ? embT : qembT;
  const int colbase = rev ? 512 : 0;
  const int eTL = (dir < 2) ? 1024 : 32;
  const int hbase = sub * 16;

  __shared__ __align__(16) u16 Wl[64 * 520];
  __shared__ float hl[512];
  __shared__ float gbuf[64];
  __shared__ float cbuf[16];

  for (int idx = tid; idx < 64 * 512; idx += 256){
    int lr = idx >> 9, k = idx & 511;
    int grow = (lr >> 4) * 512 + hbase + (lr & 15);
    Wl[lr * 520 + k] = f2bf(Wh[(size_t)grow * 512 + k]);
  }
  if (tid < 16) cbuf[tid] = 0.f;
  for (int idx = tid; idx < 512; idx += 256) hl[idx] = 0.f;
  __syncthreads();

  const int r4 = tid >> 4;      // 0..15 -> rows 4*r4+rr
  const int seg = tid & 15;     // k-pair class: pairs p = seg + 16*i
  int* mystamps = stamps + dir * 32;
  float* hdir = hglob + dir * 1024;

  for (int t = 0; t < L; ++t){
    float2 hreg[16];
#pragma unroll
    for (int i = 0; i < 16; ++i) hreg[i] = *(const float2*)&hl[2 * (seg + 16 * i)];
    float s0 = 0, s1 = 0, s2 = 0, s3 = 0;
    {
      const u16* w0 = &Wl[(4 * r4 + 0) * 520];
      const u16* w1 = &Wl[(4 * r4 + 1) * 520];
      const u16* w2 = &Wl[(4 * r4 + 2) * 520];
      const u16* w3 = &Wl[(4 * r4 + 3) * 520];
#pragma unroll
      for (int i = 0; i < 16; ++i){
        int o = 2 * (seg + 16 * i);
        u32 a0 = *(const u32*)&w0[o];
        u32 a1 = *(const u32*)&w1[o];
        u32 a2 = *(const u32*)&w2[o];
        u32 a3 = *(const u32*)&w3[o];
        float hx = hreg[i].x, hy = hreg[i].y;
        s0 = fmaf(bflo(a0), hx, s0); s0 = fmaf(bfhi(a0), hy, s0);
        s1 = fmaf(bflo(a1), hx, s1); s1 = fmaf(bfhi(a1), hy, s1);
        s2 = fmaf(bflo(a2), hx, s2); s2 = fmaf(bfhi(a2), hy, s2);
        s3 = fmaf(bflo(a3), hx, s3); s3 = fmaf(bfhi(a3), hy, s3);
      }
    }
#pragma unroll
    for (int m = 1; m < 16; m <<= 1){
      s0 += __shfl_xor(s0, m, 64); s1 += __shfl_xor(s1, m, 64);
      s2 += __shfl_xor(s2, m, 64); s3 += __shfl_xor(s3, m, 64);
    }
    const int trow = rev ? (L - 1 - t) : t;
    if (seg == 0){
      float sv[4] = {s0, s1, s2, s3};
#pragma unroll
      for (int rr = 0; rr < 4; ++rr){
        int lr = 4 * r4 + rr;
        int grow = (lr >> 4) * 512 + hbase + (lr & 15);
        gbuf[lr] = sv[rr] + xp[(size_t)trow * 2048 + grow];
      }
    }
    __syncthreads();
    if (tid < 16){
      float gi = gbuf[tid], gf = gbuf[16 + tid], gg = gbuf[32 + tid], go = gbuf[48 + tid];
      float c = sigm(gf) * cbuf[tid] + sigm(gi) * tanhf(gg);
      cbuf[tid] = c;
      float h = sigm(go) * tanhf(c);
      int col = colbase + hbase + tid;
      oe[(size_t)trow * 1024 + col] = h;
      oeT[(size_t)col * eTL + trow] = h;
      astoref(&hdir[((t + 1) & 1) * 512 + hbase + tid], h);
      __threadfence();
    }
    __syncthreads();
    if (tid == 0) astorei_rel(&mystamps[sub], t + 1);
    if (tid < 32){
      while (aloadi_acq(&mystamps[tid]) < t + 1) __builtin_amdgcn_s_sleep(1);
    }
    __syncthreads();
    for (int idx = tid; idx < 512; idx += 256)
      hl[idx] = aloadf(&hdir[((t + 1) & 1) * 512 + idx]);
    __syncthreads();
  }
}

// ---------------------------------------------------------------- decoder (persistent, 128 blocks)
#define DG 128
__device__ inline void dbar(int* st, int b, int pc, int tid){
  __syncthreads();
  if (tid == 0){
    __threadfence();
    astorei_rel(&st[b], pc);
  }
  if (tid < 64){
#pragma unroll
    for (int i = 0; i < 2; ++i){
      int idx = tid + i * 64;
      while (aloadi_acq(&st[idx]) < pc) __builtin_amdgcn_s_sleep(2);
    }
  }
  __syncthreads();
}

struct DecArgs {
  const float *emb, *embT, *qemb, *qembT;
  const float *Wimg_e, *bimg, *Wmod_img;
  const float *Wq_e, *bq, *Wmod_q;
  const float *Wmod, *bmod;
  const u16 *Wfus_bf; const float *bfus;
  const u16 *WfusI_bf, *WfusQ_bf;
  const u16 *Wid_bf, *Whd_bf; const float *b_dec;
  const u16 *Wfin_bf; const float *bfin;
  float *e_img, *m_img, *e_q, *m_q;
  float *a_img, *a_q, *ctx_img, *ctx_q;
  float *d_img, *d_q, *fs, *hdec, *scal;
  int *st; float *out; int T;
};

__global__ __launch_bounds__(256, 1) void k_dec(DecArgs A)
{
  const int b = blockIdx.x, tid = threadIdx.x;
  const int lane = tid & 63, wv = tid >> 6;
  __shared__ float hl[1024];
  __shared__ float fsl[1024];
  __shared__ float red[4];
  __shared__ float gb[32];
  __shared__ float cdec[8];
  __shared__ float aql[32];
  int pc = 0;

  // ---- P0: e_img/m_img (8 rows/block), e_q/m_q (blocks 0..31)
  {
#pragma unroll
    for (int rr = 0; rr < 2; ++rr){
      int l = b * 8 + wv * 2 + rr;
      const float* er = A.emb + (size_t)l * 1024;
      float se = 0, sm = 0;
#pragma unroll
      for (int i = 0; i < 16; ++i){
        int k = lane + (i << 6);
        float x = er[k];
        se = fmaf(x, A.Wimg_e[k], se);
        sm = fmaf(x, A.Wmod_img[k], sm);
      }
      se = wred_sum(se); sm = wred_sum(sm);
      if (lane == 0){ astoref(A.e_img + l, se + A.bimg[0]); astoref(A.m_img + l, sm); }
    }
    if (b < 32 && wv == 0){
      const float* qr = A.qemb + (size_t)b * 1024;
      float se = 0, sm = 0;
#pragma unroll
      for (int i = 0; i < 16; ++i){
        int k = lane + (i << 6);
        float x = qr[k];
        se = fmaf(x, A.Wq_e[k], se);
        sm = fmaf(x, A.Wmod_q[k], sm);
      }
      se = wred_sum(se); sm = wred_sum(sm);
      if (lane == 0){ astoref(A.e_q + b, se + A.bq[0]); astoref(A.m_q + b, sm); }
    }
  }
  pc++; dbar(A.st, b, pc, tid);

  // ---- P1: block0 softmax(e) -> a, wdot (attention is step-invariant!)
  if (b == 0){
    for (int k = tid; k < 1024; k += 256){ fsl[k] = aloadf(A.e_img + k); hl[k] = aloadf(A.m_img + k); }
    __syncthreads();
    float lm = -3.4e38f;
    for (int k = tid; k < 1024; k += 256) lm = fmaxf(lm, fsl[k]);
    float M = bred_max(lm, red, tid);
    float ls = 0, lw = 0;
    for (int k = tid; k < 1024; k += 256){
      float e = expf(fsl[k] - M);
      fsl[k] = e; ls += e; lw += e * hl[k];
    }
    float S = bred_sum(ls, red, tid);
    float W = bred_sum(lw, red, tid);
    float inv = 1.f / S;
    for (int k = tid; k < 1024; k += 256) astoref(A.a_img + k, fsl[k] * inv);
    if (tid == 0) astoref(A.scal + 2, W * inv);
    if (tid < 64){
      float ev = (lane < 32) ? aloadf(A.e_q + lane) : -3.4e38f;
      float mv = (lane < 32) ? aloadf(A.m_q + lane) : 0.f;
      float M2 = ev;
#pragma unroll
      for (int m = 32; m >= 1; m >>= 1) M2 = fmaxf(M2, __shfl_xor(M2, m, 64));
      float e = (lane < 32) ? expf(ev - M2) : 0.f;
      float S2 = wred_sum(e);
      float W2 = wred_sum(e * mv);
      if (lane < 32) astoref(A.a_q + lane, e / S2);
      if (lane == 0) astoref(A.scal + 3, W2 / S2);
    }
  }
  pc++; dbar(A.st, b, pc, tid);

  // ---- P2: ctx (once; attention constant across steps)
  if (b < 64){
    for (int k = tid; k < 1024; k += 256) hl[k] = aloadf(A.a_img + k);
    __syncthreads();
#pragma unroll
    for (int cc = 0; cc < 4; ++cc){
      int c = b * 16 + wv * 4 + cc;
      const float* eT = A.embT + (size_t)c * 1024;
      float s = 0;
#pragma unroll
      for (int i = 0; i < 16; ++i){ int l = lane + (i << 6); s = fmaf(hl[l], eT[l], s); }
      s = wred_sum(s);
      if (lane == 0) astoref(A.ctx_img + c, s);
    }
  } else {
    if (tid < 32) aql[tid] = aloadf(A.a_q + tid);
    __syncthreads();
#pragma unroll
    for (int cc = 0; cc < 4; ++cc){
      int c = (b - 64) * 16 + wv * 4 + cc;
      const float* eT = A.qembT + (size_t)c * 32;
      float s = (lane < 32) ? aql[lane] * eT[lane] : 0.f;
      s = wred_sum(s);
      if (lane == 0) astoref(A.ctx_q + c, s);
    }
  }
  pc++; dbar(A.st, b, pc, tid);

  // ---- P3: d_img/d_q (once)
  for (int k = tid; k < 1024; k += 256){ hl[k] = aloadf(A.ctx_img + k); fsl[k] = aloadf(A.ctx_q + k); }
  __syncthreads();
#pragma unroll
  for (int rr = 0; rr < 2; ++rr){
    int r = b * 8 + wv * 2 + rr;
    const u32* wi = (const u32*)(A.WfusI_bf + (size_t)r * 1024);
    const u32* wq = (const u32*)(A.WfusQ_bf + (size_t)r * 1024);
    float si = 0, sq = 0;
#pragma unroll
    for (int i = 0; i < 8; ++i){
      int u = lane + (i << 6);
      u32 a = wi[u]; u32 c = wq[u];
      float2 x = *(const float2*)&hl[2 * u];
      float2 y = *(const float2*)&fsl[2 * u];
      si = fmaf(bflo(a), x.x, si); si = fmaf(bfhi(a), x.y, si);
      sq = fmaf(bflo(c), y.x, sq); sq = fmaf(bfhi(c), y.y, sq);
    }
    si = wred_sum(si); sq = wred_sum(sq);
    if (lane == 0){ astoref(A.d_img + r, si); astoref(A.d_q + r, sq); }
  }
  pc++; dbar(A.st, b, pc, tid);

  // stage h0 = 0, c = 0
  for (int k = tid; k < 1024; k += 256) hl[k] = aloadf(A.hdec + k);
  if (tid < 8) cdec[tid] = 0.f;
  __syncthreads();

  // ---- decode loop
  for (int t = 0; t < A.T; ++t){
    // PH1: block0: tmp-dot + modality mix; others: logits_{t-1} = Wfin @ h_t
    if (b == 0){
      float part = 0;
      for (int k = tid; k < 1024; k += 256) part = fmaf(A.Wmod[k], hl[k], part);
      float tmp = bred_sum(part, red, tid);
      if (tid == 0){
        tmp += A.bmod[0];
        float wi = tanhf(tmp + aloadf(A.scal + 2));
        float wq = tanhf(tmp + aloadf(A.scal + 3));
        float mx = fmaxf(wi, wq);
        float e0 = expf(wi - mx), e1 = expf(wq - mx);
        float inv = 1.f / (e0 + e1);
        astoref(A.scal + 0, e0 * inv);
        astoref(A.scal + 1, e1 * inv);
      }
    } else if (t > 0){
      int gw = (b - 1) * 4 + wv;
      for (int r = gw; r < 32000; r += 508){
        const u32* wr = (const u32*)(A.Wfin_bf + (size_t)r * 1024);
        float s = 0;
#pragma unroll
        for (int i = 0; i < 8; ++i){
          int u = lane + (i << 6);
          u32 a = wr[u];
          float2 x = *(const float2*)&hl[2 * u];
          s = fmaf(bflo(a), x.x, s); s = fmaf(bfhi(a), x.y, s);
        }
        s = wred_sum(s);
        if (lane == 0) A.out[(size_t)(t - 1) * 32000 + r] = s + A.bfin[r];
      }
    }
    pc++; dbar(A.st, b, pc, tid);

    // PH2: fs rows
    {
      float mw0 = aloadf(A.scal + 0), mw1 = aloadf(A.scal + 1);
#pragma unroll
      for (int rr = 0; rr < 2; ++rr){
        int r = b * 8 + wv * 2 + rr;
        const u32* wr = (const u32*)(A.Wfus_bf + (size_t)r * 1024);
        float s = 0;
#pragma unroll
        for (int i = 0; i < 8; ++i){
          int u = lane + (i << 6);
          u32 a = wr[u];
          float2 x = *(const float2*)&hl[2 * u];
          s = fmaf(bflo(a), x.x, s); s = fmaf(bfhi(a), x.y, s);
        }
        s = wred_sum(s);
        if (lane == 0){
          float v = tanhf(s + A.bfus[r] + mw0 * aloadf(A.d_img + r) + mw1 * aloadf(A.d_q + r));
          astoref(A.fs + r, v);
        }
      }
    }
    pc++; dbar(A.st, b, pc, tid);

    // PH3: decoder LSTM step
    for (int k = tid; k < 1024; k += 256) fsl[k] = aloadf(A.fs + k);
    __syncthreads();
#pragma unroll
    for (int rr = 0; rr < 8; ++rr){
      int lr = wv * 8 + rr;                       // 0..31
      int gr = (lr >> 3) * 1024 + b * 8 + (lr & 7);
      const u32* w1 = (const u32*)(A.Wid_bf + (size_t)gr * 1024);
      const u32* w2 = (const u32*)(A.Whd_bf + (size_t)gr * 1024);
      float s = 0;
#pragma unroll
      for (int i = 0; i < 8; ++i){
        int u = lane + (i << 6);
        u32 a = w1[u]; u32 c = w2[u];
        float2 x = *(const float2*)&fsl[2 * u];
        float2 y = *(const float2*)&hl[2 * u];
        s = fmaf(bflo(a), x.x, s); s = fmaf(bfhi(a), x.y, s);
        s = fmaf(bflo(c), y.x, s); s = fmaf(bfhi(c), y.y, s);
      }
      s = wred_sum(s);
      if (lane == 0) gb[lr] = s + A.b_dec[gr];
    }
    __syncthreads();
    if (tid < 8){
      float gi = gb[tid], gf = gb[8 + tid], gg = gb[16 + tid], go = gb[24 + tid];
      float c = sigm(gf) * cdec[tid] + sigm(gi) * tanhf(gg);
      cdec[tid] = c;
      float h = sigm(go) * tanhf(c);
      astoref(A.hdec + b * 8 + tid, h);
      __threadfence();
    }
    pc++; dbar(A.st, b, pc, tid);
    for (int k = tid; k < 1024; k += 256) hl[k] = aloadf(A.hdec + k);
    __syncthreads();
  }

  // final logits (h_T)
  {
    int gw = b * 4 + wv;
    for (int r = gw; r < 32000; r += 512){
      const u32* wr = (const u32*)(A.Wfin_bf + (size_t)r * 1024);
      float s = 0;
#pragma unroll
      for (int i = 0; i < 8; ++i){
        int u = lane + (i << 6);
        u32 a = wr[u];
        float2 x = *(const float2*)&hl[2 * u];
        s = fmaf(bflo(a), x.x, s); s = fmaf(bfhi(a), x.y, s);
      }
      s = wred_sum(s);
      if (lane == 0) A.out[(size_t)(A.T - 1) * 32000 + r] = s + A.bfin[r];
    }
  }
}

// ---------------------------------------------------------------- host
extern "C" void kernel_launch(void* const* d_in, const int* in_sizes, int n_in,
                              void* d_out, int out_size, void* d_ws, size_t ws_size,
                              hipStream_t stream)
{
  const float* img_feats = (const float*)d_in[0];
  const float* q_feats   = (const float*)d_in[1];
  const float* Wi_imgf = (const float*)d_in[2];
  const float* Wh_imgf = (const float*)d_in[3];
  const float* b_imgf  = (const float*)d_in[4];
  const float* Wi_imgb = (const float*)d_in[5];
  const float* Wh_imgb = (const float*)d_in[6];
  const float* b_imgb  = (const float*)d_in[7];
  const float* Wi_qf = (const float*)d_in[8];
  const float* Wh_qf = (const float*)d_in[9];
  const float* b_qf  = (const float*)d_in[10];
  const float* Wi_qb = (const float*)d_in[11];
  const float* Wh_qb = (const float*)d_in[12];
  const float* b_qb  = (const float*)d_in[13];
  const float* Wimg_e = (const float*)d_in[15];
  const float* bimg   = (const float*)d_in[16];
  const float* Wq_e   = (const float*)d_in[18];
  const float* bq     = (const float*)d_in[19];
  const float* Wmod   = (const float*)d_in[20];
  const float* bmod   = (const float*)d_in[21];
  const float* Wmod_img = (const float*)d_in[22];
  const float* Wmod_q   = (const float*)d_in[23];
  const float* Wfus_img = (const float*)d_in[24];
  const float* Wfus_q   = (const float*)d_in[25];
  const float* Wfus     = (const float*)d_in[26];
  const float* bfus     = (const float*)d_in[27];
  const float* Wi_dec = (const float*)d_in[28];
  const float* Wh_dec = (const float*)d_in[29];
  const float* b_dec  = (const float*)d_in[30];
  const float* Wfin = (const float*)d_in[31];
  const float* bfin = (const float*)d_in[32];
  const int T = out_size / 32000;

  char* ws = (char*)d_ws;
  size_t off = 0;
  auto alloc = [&](size_t bytes){ size_t o = off; off += (bytes + 255) & ~(size_t)255; return o; };
  const size_t oA    = alloc(1024ull * 2048 * 2);
  const size_t oWiF  = alloc(2048ull * 2048 * 2);
  const size_t oWiB  = alloc(2048ull * 2048 * 2);
  const size_t oWfin = alloc(32000ull * 1024 * 2);
  const size_t oWfu  = alloc(1024ull * 1024 * 2);
  const size_t oWfI  = alloc(1024ull * 1024 * 2);
  const size_t oWfQ  = alloc(1024ull * 1024 * 2);
  const size_t oWid  = alloc(4096ull * 1024 * 2);
  const size_t oWhd  = alloc(4096ull * 1024 * 2);
  const size_t oxpF  = alloc(1024ull * 2048 * 4);
  const size_t oxpB  = alloc(1024ull * 2048 * 4);
  const size_t oxpQF = alloc(32ull * 2048 * 4);
  const size_t oxpQB = alloc(32ull * 2048 * 4);
  const size_t oemb  = alloc(1024ull * 1024 * 4);
  const size_t oembT = alloc(1024ull * 1024 * 4);
  const size_t oqemb = alloc(32ull * 1024 * 4);
  const size_t oqembT= alloc(1024ull * 32 * 4);
  const size_t oeimg = alloc(1024 * 4);
  const size_t omimg = alloc(1024 * 4);
  const size_t oeq   = alloc(32 * 4);
  const size_t omq   = alloc(32 * 4);
  const size_t oaimg = alloc(1024 * 4);
  const size_t oaq   = alloc(32 * 4);
  const size_t octxi = alloc(1024 * 4);
  const size_t octxq = alloc(1024 * 4);
  const size_t odimg = alloc(1024 * 4);
  const size_t odq   = alloc(1024 * 4);
  const size_t ofs   = alloc(1024 * 4);
  const size_t oCTRL = off;
  const size_t ohscan = alloc(4ull * 2 * 512 * 4);
  const size_t ohdec  = alloc(1024 * 4);
  const size_t osst   = alloc(128 * 4);
  const size_t odst   = alloc(128 * 4);
  const size_t oscal  = alloc(64 * 4);
  const size_t ctrlBytes = off - oCTRL;
  (void)ws_size; (void)n_in; (void)in_sizes;

  hipMemsetAsync(ws + oCTRL, 0, ctrlBytes, stream);

  auto cvt = [&](const float* s, size_t o, long n){
    int n4 = (int)(n >> 2);
    int g = (n4 + 255) / 256; if (g > 2048) g = 2048;
    k_cvt<<<dim3(g), dim3(256), 0, stream>>>(s, (u16*)(ws + o), n4);
  };
  cvt(img_feats, oA, 1024L * 2048);
  cvt(Wi_imgf, oWiF, 2048L * 2048);
  cvt(Wi_imgb, oWiB, 2048L * 2048);
  cvt(Wfin, oWfin, 32000L * 1024);
  cvt(Wfus, oWfu, 1024L * 1024);
  cvt(Wfus_img, oWfI, 1024L * 1024);
  cvt(Wfus_q, oWfQ, 1024L * 1024);
  cvt(Wi_dec, oWid, 4096L * 1024);
  cvt(Wh_dec, oWhd, 4096L * 1024);

  k_gemm_xp<<<dim3(16, 8, 2), dim3(256), 0, stream>>>(
      (const u16*)(ws + oA), (const u16*)(ws + oWiF), (const u16*)(ws + oWiB),
      b_imgf, b_imgb, (float*)(ws + oxpF), (float*)(ws + oxpB));

  k_qxp<<<dim3(32, 2), dim3(256), 0, stream>>>(
      q_feats, Wi_qf, Wi_qb, b_qf, b_qb,
      (float*)(ws + oxpQF), (float*)(ws + oxpQB));

  k_scan<<<dim3(128), dim3(256), 0, stream>>>(
      Wh_imgf, Wh_imgb, Wh_qf, Wh_qb,
      (const float*)(ws + oxpF), (const float*)(ws + oxpB),
      (const float*)(ws + oxpQF), (const float*)(ws + oxpQB),
      (float*)(ws + oemb), (float*)(ws + oembT),
      (float*)(ws + oqemb), (float*)(ws + oqembT),
      (float*)(ws + ohscan), (int*)(ws + osst));

  DecArgs DA;
  DA.emb = (const float*)(ws + oemb); DA.embT = (const float*)(ws + oembT);
  DA.qemb = (const float*)(ws + oqemb); DA.qembT = (const float*)(ws + oqembT);
  DA.Wimg_e = Wimg_e; DA.bimg = bimg; DA.Wmod_img = Wmod_img;
  DA.Wq_e = Wq_e; DA.bq = bq; DA.Wmod_q = Wmod_q;
  DA.Wmod = Wmod; DA.bmod = bmod;
  DA.Wfus_bf = (const u16*)(ws + oWfu); DA.bfus = bfus;
  DA.WfusI_bf = (const u16*)(ws + oWfI); DA.WfusQ_bf = (const u16*)(ws + oWfQ);
  DA.Wid_bf = (const u16*)(ws + oWid); DA.Whd_bf = (const u16*)(ws + oWhd); DA.b_dec = b_dec;
  DA.Wfin_bf = (const u16*)(ws + oWfin); DA.bfin = bfin;
  DA.e_img = (float*)(ws + oeimg); DA.m_img = (float*)(ws + omimg);
  DA.e_q = (float*)(ws + oeq); DA.m_q = (float*)(ws + omq);
  DA.a_img = (float*)(ws + oaimg); DA.a_q = (float*)(ws + oaq);
  DA.ctx_img = (float*)(ws + octxi); DA.ctx_q = (float*)(ws + octxq);
  DA.d_img = (float*)(ws + odimg); DA.d_q = (float*)(ws + odq);
  DA.fs = (float*)(ws + ofs); DA.hdec = (float*)(ws + ohdec);
  DA.scal = (float*)(ws + oscal); DA.st = (int*)(ws + odst);
  DA.out = (float*)d_out; DA.T = T;

  k_dec<<<dim3(DG), dim3(256), 0, stream>>>(DA);
}

// Round 2
// 4161.237 us; speedup vs baseline: 2.2951x; 2.2951x over previous
//
#include <hip/hip_runtime.h>
#include <hip/hip_bf16.h>

typedef unsigned int  u32;
typedef unsigned short u16;
typedef unsigned long long u64;
typedef float f32x4 __attribute__((ext_vector_type(4)));
typedef short bf16x8 __attribute__((ext_vector_type(8)));
typedef u32 u32x4 __attribute__((ext_vector_type(4)));

#define AGENT __HIP_MEMORY_SCOPE_AGENT
__device__ inline float aloadf(const float* p){ return __hip_atomic_load(p, __ATOMIC_RELAXED, AGENT); }
__device__ inline void  astoref(float* p, float v){ __hip_atomic_store(p, v, __ATOMIC_RELAXED, AGENT); }
__device__ inline int   aloadi(const int* p){ return __hip_atomic_load(p, __ATOMIC_RELAXED, AGENT); }
__device__ inline void  astorei_rel(int* p, int v){ __hip_atomic_store(p, v, __ATOMIC_RELEASE, AGENT); }
__device__ inline u64   aload64(const u64* p){ return __hip_atomic_load(p, __ATOMIC_RELAXED, AGENT); }
__device__ inline void  astore64(u64* p, u64 v){ __hip_atomic_store(p, v, __ATOMIC_RELAXED, AGENT); }
__device__ inline u64   tagpack(u32 tag, float v){ return ((u64)tag << 32) | (u64)__float_as_uint(v); }

__device__ __host__ inline u16 f2bf(float f){
  u32 u = __builtin_bit_cast(u32, f);
  u += 0x7fffu + ((u >> 16) & 1u);
  return (u16)(u >> 16);
}
__device__ inline float bflo(u32 a){ return __uint_as_float(a << 16); }
__device__ inline float bfhi(u32 a){ return __uint_as_float(a & 0xffff0000u); }
__device__ inline float sigm(float x){ return 1.f/(1.f + expf(-x)); }

__device__ inline float wred_sum(float v){
#pragma unroll
  for (int m = 32; m >= 1; m >>= 1) v += __shfl_xor(v, m, 64);
  return v;
}
__device__ inline float bred_sum(float v, float* red, int tid){
  v = wred_sum(v);
  if ((tid & 63) == 0) red[tid >> 6] = v;
  __syncthreads();
  float r = red[0] + red[1] + red[2] + red[3];
  __syncthreads();
  return r;
}
__device__ inline float bred_max(float v, float* red, int tid){
#pragma unroll
  for (int m = 32; m >= 1; m >>= 1) v = fmaxf(v, __shfl_xor(v, m, 64));
  if ((tid & 63) == 0) red[tid >> 6] = v;
  __syncthreads();
  float r = fmaxf(fmaxf(red[0], red[1]), fmaxf(red[2], red[3]));
  __syncthreads();
  return r;
}

// dot of a 1024-wide bf16 row with 1024-float LDS vector; partial per lane
// (caller must wred_sum). Row loaded as 2x dwordx4.
__device__ inline float dot1024(const u16* __restrict__ row, const float* h, int lane){
  const u32x4* wr = (const u32x4*)row;
  float s = 0.f;
#pragma unroll
  for (int i = 0; i < 2; ++i){
    int j = lane + (i << 6);
    u32x4 a = wr[j];
    const float* hp = h + (j << 3);
    float4 x0 = *(const float4*)hp;
    float4 x1 = *(const float4*)(hp + 4);
    s = fmaf(bflo(a.x), x0.x, s); s = fmaf(bfhi(a.x), x0.y, s);
    s = fmaf(bflo(a.y), x0.z, s); s = fmaf(bfhi(a.y), x0.w, s);
    s = fmaf(bflo(a.z), x1.x, s); s = fmaf(bfhi(a.z), x1.y, s);
    s = fmaf(bflo(a.w), x1.z, s); s = fmaf(bfhi(a.w), x1.w, s);
  }
  return s;
}

// ---------------------------------------------------------------- fp32 -> bf16
__global__ void k_cvt(const float* __restrict__ s, u16* __restrict__ d, int n4){
  int i = blockIdx.x * 256 + threadIdx.x;
  int stride = gridDim.x * 256;
  const float4* s4 = (const float4*)s;
  for (; i < n4; i += stride){
    float4 v = s4[i];
    ushort4 o;
    o.x = f2bf(v.x); o.y = f2bf(v.y); o.z = f2bf(v.z); o.w = f2bf(v.w);
    ((ushort4*)d)[i] = o;
  }
}

// ---------------------------------------------------------------- img xp GEMM
__global__ __launch_bounds__(256, 1) void k_gemm_xp(
    const u16* __restrict__ A,
    const u16* __restrict__ B0, const u16* __restrict__ B1,
    const float* __restrict__ bias0, const float* __restrict__ bias1,
    float* __restrict__ C0, float* __restrict__ C1)
{
  const int K = 2048, N = 2048;
  const int bx = blockIdx.x, by = blockIdx.y, z = blockIdx.z;
  const u16* B = z ? B1 : B0;
  const float* bias = z ? bias1 : bias0;
  float* C = z ? C1 : C0;
  const int tid = threadIdx.x;
  const int lane = tid & 63, wv = tid >> 6;
  const int m0 = by * 128, n0 = bx * 128;
  const int wm = (wv >> 1) * 64, wn = (wv & 1) * 64;

  __shared__ __align__(16) u16 lA[128 * 32];
  __shared__ __align__(16) u16 lB[128 * 32];

  f32x4 acc[4][4];
#pragma unroll
  for (int i = 0; i < 4; ++i)
#pragma unroll
    for (int j = 0; j < 4; ++j) acc[i][j] = (f32x4){0.f, 0.f, 0.f, 0.f};

  const int lrow = tid >> 2;
  const int lcol = (tid & 3) * 8;
  const u16* aBase = A + (size_t)(m0 + lrow) * K + lcol;
  const u16* bBase = B + (size_t)(n0 + lrow) * K + lcol;

  for (int kk = 0; kk < K; kk += 32){
#pragma unroll
    for (int io = 0; io < 2; ++io){
      __builtin_amdgcn_global_load_lds(
        (const __attribute__((address_space(1))) void*)(aBase + (size_t)io * 64 * K + kk),
        (__attribute__((address_space(3))) void*)((char*)lA + wv * 1024 + io * 4096), 16, 0, 0);
      __builtin_amdgcn_global_load_lds(
        (const __attribute__((address_space(1))) void*)(bBase + (size_t)io * 64 * K + kk),
        (__attribute__((address_space(3))) void*)((char*)lB + wv * 1024 + io * 4096), 16, 0, 0);
    }
    asm volatile("s_waitcnt vmcnt(0)");
    __syncthreads();

    bf16x8 af[4], bfr[4];
#pragma unroll
    for (int i = 0; i < 4; ++i){
      af[i]  = *(const bf16x8*)&lA[(wm + i * 16 + (lane & 15)) * 32 + (lane >> 4) * 8];
      bfr[i] = *(const bf16x8*)&lB[(wn + i * 16 + (lane & 15)) * 32 + (lane >> 4) * 8];
    }
#pragma unroll
    for (int i = 0; i < 4; ++i)
#pragma unroll
      for (int j = 0; j < 4; ++j)
        acc[i][j] = __builtin_amdgcn_mfma_f32_16x16x32_bf16(af[i], bfr[j], acc[i][j], 0, 0, 0);
    __syncthreads();
  }

  const int rbase = (lane >> 4) * 4;
  const int ccol = lane & 15;
#pragma unroll
  for (int i = 0; i < 4; ++i)
#pragma unroll
    for (int j = 0; j < 4; ++j){
      int col = n0 + wn + j * 16 + ccol;
      float bv = bias[col];
#pragma unroll
      for (int r2 = 0; r2 < 4; ++r2){
        int row = m0 + wm + i * 16 + rbase + r2;
        C[(size_t)row * N + col] = acc[i][j][r2] + bv;
      }
    }
}

// ---------------------------------------------------------------- q xp (small fp32 GEMM)
__global__ __launch_bounds__(256, 1) void k_qxp(
    const float* __restrict__ qf,
    const float* __restrict__ W0, const float* __restrict__ W1,
    const float* __restrict__ bb0, const float* __restrict__ bb1,
    float* __restrict__ o0, float* __restrict__ o1)
{
  const int bx = blockIdx.x;
  const int z = blockIdx.y;
  const float* W = z ? W1 : W0;
  const float* bb = z ? bb1 : bb0;
  float* o = z ? o1 : o0;
  const int tid = threadIdx.x;
  __shared__ float xs[32 * 301];
  __shared__ float Ws[64 * 301];
  for (int idx = tid; idx < 32 * 300; idx += 256){
    int m = idx / 300, k = idx - m * 300;
    xs[m * 301 + k] = qf[idx];
  }
  for (int idx = tid; idx < 64 * 300; idx += 256){
    int j = idx / 300, k = idx - j * 300;
    Ws[j * 301 + k] = W[(size_t)(bx * 64 + j) * 300 + k];
  }
  __syncthreads();
  for (int i = 0; i < 8; ++i){
    int idx = tid + i * 256;
    int nl = idx >> 5, m = idx & 31;
    float s = 0;
    for (int k = 0; k < 300; ++k) s = fmaf(xs[m * 301 + k], Ws[nl * 301 + k], s);
    o[(size_t)m * 2048 + bx * 64 + nl] = s + bb[bx * 64 + nl];
  }
}

// ---------------------------------------------------------------- LSTM scans
// 32 blocks/direction. Cross-block h exchange via TAGGED 64-bit words
// (tag = t+1 in high 32, float bits low): one L3 round trip, no fences.
// 2-slot parity buffer per direction.
__global__ __launch_bounds__(256, 1) void k_scan(
    const float* __restrict__ WhA, const float* __restrict__ WhB,
    const float* __restrict__ WhC, const float* __restrict__ WhD,
    const float* __restrict__ xpA, const float* __restrict__ xpB,
    const float* __restrict__ xpC, const float* __restrict__ xpD,
    float* __restrict__ emb, float* __restrict__ embT,
    float* __restrict__ qemb, float* __restrict__ qembT,
    u64* hcomm /* [4][2][512] */)
{
  const int tid = threadIdx.x;
  const int dir = blockIdx.x >> 5;
  const int sub = blockIdx.x & 31;
  const float* Wh = dir == 0 ? WhA : dir == 1 ? WhB : dir == 2 ? WhC : WhD;
  const float* xp = dir == 0 ? xpA : dir == 1 ? xpB : dir == 2 ? xpC : xpD;
  const int L = (dir < 2) ? 1024 : 32;
  const int rev = dir & 1;
  float* oe  = (dir < 2) ? emb  : qemb;
  float* oeT = (dir < 2) ? embT : qembT;
  const int colbase = rev ? 512 : 0;
  const int eTL = (dir < 2) ? 1024 : 32;
  const int hbase = sub * 16;

  __shared__ __align__(16) u16 Wl[64 * 520];
  __shared__ float hl[512];
  __shared__ float gbuf[64];
  __shared__ float cbuf[16];

  for (int idx = tid; idx < 64 * 512; idx += 256){
    int lr = idx >> 9, k = idx & 511;
    int grow = (lr >> 4) * 512 + hbase + (lr & 15);
    Wl[lr * 520 + k] = f2bf(Wh[(size_t)grow * 512 + k]);
  }
  if (tid < 16) cbuf[tid] = 0.f;
  for (int idx = tid; idx < 512; idx += 256) hl[idx] = 0.f;
  __syncthreads();

  const int r4 = tid >> 4;
  const int seg = tid & 15;

  int grows[4];
#pragma unroll
  for (int rr = 0; rr < 4; ++rr){
    int lr = 4 * r4 + rr;
    grows[rr] = (lr >> 4) * 512 + hbase + (lr & 15);
  }
  float xpv[4];
  if (seg == 0){
    int t0 = rev ? (L - 1) : 0;
#pragma unroll
    for (int rr = 0; rr < 4; ++rr) xpv[rr] = xp[(size_t)t0 * 2048 + grows[rr]];
  }

  for (int t = 0; t < L; ++t){
    float2 hreg[16];
#pragma unroll
    for (int i = 0; i < 16; ++i) hreg[i] = *(const float2*)&hl[2 * (seg + 16 * i)];
    float s0 = 0, s1 = 0, s2 = 0, s3 = 0;
    {
      const u16* w0 = &Wl[(4 * r4 + 0) * 520];
      const u16* w1 = &Wl[(4 * r4 + 1) * 520];
      const u16* w2 = &Wl[(4 * r4 + 2) * 520];
      const u16* w3 = &Wl[(4 * r4 + 3) * 520];
#pragma unroll
      for (int i = 0; i < 16; ++i){
        int o = 2 * (seg + 16 * i);
        u32 a0 = *(const u32*)&w0[o];
        u32 a1 = *(const u32*)&w1[o];
        u32 a2 = *(const u32*)&w2[o];
        u32 a3 = *(const u32*)&w3[o];
        float hx = hreg[i].x, hy = hreg[i].y;
        s0 = fmaf(bflo(a0), hx, s0); s0 = fmaf(bfhi(a0), hy, s0);
        s1 = fmaf(bflo(a1), hx, s1); s1 = fmaf(bfhi(a1), hy, s1);
        s2 = fmaf(bflo(a2), hx, s2); s2 = fmaf(bfhi(a2), hy, s2);
        s3 = fmaf(bflo(a3), hx, s3); s3 = fmaf(bfhi(a3), hy, s3);
      }
    }
#pragma unroll
    for (int m = 1; m < 16; m <<= 1){
      s0 += __shfl_xor(s0, m, 64); s1 += __shfl_xor(s1, m, 64);
      s2 += __shfl_xor(s2, m, 64); s3 += __shfl_xor(s3, m, 64);
    }
    const int trow = rev ? (L - 1 - t) : t;
    if (seg == 0){
      float sv[4] = {s0, s1, s2, s3};
#pragma unroll
      for (int rr = 0; rr < 4; ++rr) gbuf[4 * r4 + rr] = sv[rr] + xpv[rr];
    }
    // prefetch next step's xp (completes under the poll window)
    if (seg == 0 && t + 1 < L){
      int tn = rev ? (L - 2 - t) : (t + 1);
#pragma unroll
      for (int rr = 0; rr < 4; ++rr) xpv[rr] = xp[(size_t)tn * 2048 + grows[rr]];
    }
    __syncthreads();
    const int par = (t + 1) & 1;
    u64* hc = hcomm + ((size_t)dir * 2 + par) * 512;
    if (tid < 16){
      float gi = gbuf[tid], gf = gbuf[16 + tid], gg = gbuf[32 + tid], go = gbuf[48 + tid];
      float c = sigm(gf) * cbuf[tid] + sigm(gi) * tanhf(gg);
      cbuf[tid] = c;
      float h = sigm(go) * tanhf(c);
      astore64(&hc[hbase + tid], tagpack((u32)(t + 1), h));   // publish FIRST
      int col = colbase + hbase + tid;
      oe[(size_t)trow * 1024 + col] = h;
      oeT[(size_t)col * eTL + trow] = h;
    }
    const u32 want = (u32)(t + 1);
    u64 w0 = aload64(&hc[tid]);
    u64 w1 = aload64(&hc[tid + 256]);
    while ((u32)(w0 >> 32) != want) w0 = aload64(&hc[tid]);
    while ((u32)(w1 >> 32) != want) w1 = aload64(&hc[tid + 256]);
    hl[tid] = __uint_as_float((u32)w0);
    hl[tid + 256] = __uint_as_float((u32)w1);
    __syncthreads();
  }
}

// ---------------------------------------------------------------- decoder
#define DG 128
// prologue-only barrier: release stamp + RELAXED spin (all data moves via
// agent-scope atomics, which bypass caches, so no acquire needed)
__device__ inline void dbar(int* st, int b, int pc, int tid){
  __syncthreads();
  if (tid == 0) astorei_rel(&st[b], pc);
  if (tid < 64){
#pragma unroll
    for (int i = 0; i < 2; ++i){
      int idx = tid + i * 64;
      while (aloadi(&st[idx]) < pc) {}
    }
  }
  __syncthreads();
}

struct DecArgs {
  const float *emb, *embT, *qemb, *qembT;
  const float *Wimg_e, *bimg, *Wmod_img;
  const float *Wq_e, *bq, *Wmod_q;
  const float *Wmod, *bmod;
  const u16 *Wfus_bf; const float *bfus;
  const u16 *WfusI_bf, *WfusQ_bf;
  const u16 *Wid_bf, *Whd_bf; const float *b_dec;
  const u16 *Wfin_bf; const float *bfin;
  float *e_img, *m_img, *e_q, *m_q;
  float *a_img, *a_q, *ctx_img, *ctx_q;
  float *d_img, *d_q, *scal;
  u64 *tscal, *tfs, *thdec;
  int *st; float *out; int T;
};

__global__ __launch_bounds__(256, 1) void k_dec(DecArgs A)
{
  const int b = blockIdx.x, tid = threadIdx.x;
  const int lane = tid & 63, wv = tid >> 6;
  __shared__ __align__(16) float hl[1024];
  __shared__ __align__(16) float fsl[1024];
  __shared__ float red[4];
  __shared__ float gb[32];
  __shared__ float cdec[8];
  __shared__ float aql[32];
  __shared__ float mwl[2];
  int pc = 0;

  // ---- P0: e_img/m_img (8 rows/block), e_q/m_q (blocks 0..31)
  {
#pragma unroll
    for (int rr = 0; rr < 2; ++rr){
      int l = b * 8 + wv * 2 + rr;
      const float* er = A.emb + (size_t)l * 1024;
      float se = 0, sm = 0;
#pragma unroll
      for (int i = 0; i < 16; ++i){
        int k = lane + (i << 6);
        float x = er[k];
        se = fmaf(x, A.Wimg_e[k], se);
        sm = fmaf(x, A.Wmod_img[k], sm);
      }
      se = wred_sum(se); sm = wred_sum(sm);
      if (lane == 0){ astoref(A.e_img + l, se + A.bimg[0]); astoref(A.m_img + l, sm); }
    }
    if (b < 32 && wv == 0){
      const float* qr = A.qemb + (size_t)b * 1024;
      float se = 0, sm = 0;
#pragma unroll
      for (int i = 0; i < 16; ++i){
        int k = lane + (i << 6);
        float x = qr[k];
        se = fmaf(x, A.Wq_e[k], se);
        sm = fmaf(x, A.Wmod_q[k], sm);
      }
      se = wred_sum(se); sm = wred_sum(sm);
      if (lane == 0){ astoref(A.e_q + b, se + A.bq[0]); astoref(A.m_q + b, sm); }
    }
  }
  pc++; dbar(A.st, b, pc, tid);

  // ---- P1: block0 softmax(e) -> a (attention is step-invariant)
  if (b == 0){
    for (int k = tid; k < 1024; k += 256){ fsl[k] = aloadf(A.e_img + k); hl[k] = aloadf(A.m_img + k); }
    __syncthreads();
    float lm = -3.4e38f;
    for (int k = tid; k < 1024; k += 256) lm = fmaxf(lm, fsl[k]);
    float M = bred_max(lm, red, tid);
    float ls = 0, lw = 0;
    for (int k = tid; k < 1024; k += 256){
      float e = expf(fsl[k] - M);
      fsl[k] = e; ls += e; lw += e * hl[k];
    }
    float S = bred_sum(ls, red, tid);
    float W = bred_sum(lw, red, tid);
    float inv = 1.f / S;
    for (int k = tid; k < 1024; k += 256) astoref(A.a_img + k, fsl[k] * inv);
    if (tid == 0) astoref(A.scal + 2, W * inv);
    if (tid < 64){
      float ev = (lane < 32) ? aloadf(A.e_q + lane) : -3.4e38f;
      float mv = (lane < 32) ? aloadf(A.m_q + lane) : 0.f;
      float M2 = ev;
#pragma unroll
      for (int m = 32; m >= 1; m >>= 1) M2 = fmaxf(M2, __shfl_xor(M2, m, 64));
      float e = (lane < 32) ? expf(ev - M2) : 0.f;
      float S2 = wred_sum(e);
      float W2 = wred_sum(e * mv);
      if (lane < 32) astoref(A.a_q + lane, e / S2);
      if (lane == 0) astoref(A.scal + 3, W2 / S2);
    }
  }
  pc++; dbar(A.st, b, pc, tid);

  // ---- P2: ctx (once)
  if (b < 64){
    for (int k = tid; k < 1024; k += 256) hl[k] = aloadf(A.a_img + k);
    __syncthreads();
#pragma unroll
    for (int cc = 0; cc < 4; ++cc){
      int c = b * 16 + wv * 4 + cc;
      const float* eT = A.embT + (size_t)c * 1024;
      float s = 0;
#pragma unroll
      for (int i = 0; i < 16; ++i){ int l = lane + (i << 6); s = fmaf(hl[l], eT[l], s); }
      s = wred_sum(s);
      if (lane == 0) astoref(A.ctx_img + c, s);
    }
  } else {
    if (tid < 32) aql[tid] = aloadf(A.a_q + tid);
    __syncthreads();
#pragma unroll
    for (int cc = 0; cc < 4; ++cc){
      int c = (b - 64) * 16 + wv * 4 + cc;
      const float* eT = A.qembT + (size_t)c * 32;
      float s = (lane < 32) ? aql[lane] * eT[lane] : 0.f;
      s = wred_sum(s);
      if (lane == 0) astoref(A.ctx_q + c, s);
    }
  }
  pc++; dbar(A.st, b, pc, tid);

  // ---- P3: d_img/d_q (once)
  for (int k = tid; k < 1024; k += 256){ hl[k] = aloadf(A.ctx_img + k); fsl[k] = aloadf(A.ctx_q + k); }
  __syncthreads();
#pragma unroll
  for (int rr = 0; rr < 2; ++rr){
    int r = b * 8 + wv * 2 + rr;
    float si = dot1024(A.WfusI_bf + (size_t)r * 1024, hl, lane);
    float sq = dot1024(A.WfusQ_bf + (size_t)r * 1024, fsl, lane);
    si = wred_sum(si); sq = wred_sum(sq);
    if (lane == 0){ astoref(A.d_img + r, si); astoref(A.d_q + r, sq); }
  }
  pc++; dbar(A.st, b, pc, tid);

  // cache per-block row constants
  float dimg_r[2], dq_r[2], bfus_r[2];
#pragma unroll
  for (int rr = 0; rr < 2; ++rr){
    int r = b * 8 + wv * 2 + rr;
    dimg_r[rr] = aloadf(A.d_img + r);
    dq_r[rr]   = aloadf(A.d_q + r);
    bfus_r[rr] = A.bfus[r];
  }
  const float sc2 = aloadf(A.scal + 2), sc3 = aloadf(A.scal + 3);

  // h0 = 0, c0 = 0
  for (int k = tid; k < 1024; k += 256) hl[k] = 0.f;
  if (tid < 8) cdec[tid] = 0.f;
  __syncthreads();

  // ---- decode loop: all sync via tagged words, no barriers
  for (int t = 0; t < A.T; ++t){
    const u32 want = (u32)(t + 1);
    // PH1: block0 -> modality weights; others -> logits_{t-1} = Wfin @ h_t
    if (b == 0){
      float part = 0;
      for (int k = tid; k < 1024; k += 256) part = fmaf(A.Wmod[k], hl[k], part);
      float tmp = bred_sum(part, red, tid);
      if (tid == 0){
        tmp += A.bmod[0];
        float wi = tanhf(tmp + sc2);
        float wq = tanhf(tmp + sc3);
        float mx = fmaxf(wi, wq);
        float e0 = expf(wi - mx), e1 = expf(wq - mx);
        float inv = 1.f / (e0 + e1);
        astore64(&A.tscal[0], tagpack(want, e0 * inv));
        astore64(&A.tscal[1], tagpack(want, e1 * inv));
      }
    } else if (t > 0){
      int gw = (b - 1) * 4 + wv;
      for (int r = gw; r < 32000; r += 508){
        float s = dot1024(A.Wfin_bf + (size_t)r * 1024, hl, lane);
        s = wred_sum(s);
        if (lane == 0) A.out[(size_t)(t - 1) * 32000 + r] = s + A.bfin[r];
      }
    }

    // PH2: fs rows — matvec first (independent of mw), then poll mw
    float sfus[2];
#pragma unroll
    for (int rr = 0; rr < 2; ++rr){
      int r = b * 8 + wv * 2 + rr;
      sfus[rr] = wred_sum(dot1024(A.Wfus_bf + (size_t)r * 1024, hl, lane));
    }
    if (tid < 2){
      u64 w = aload64(&A.tscal[tid]);
      while ((u32)(w >> 32) != want) w = aload64(&A.tscal[tid]);
      mwl[tid] = __uint_as_float((u32)w);
    }
    __syncthreads();
    {
      float mw0 = mwl[0], mw1 = mwl[1];
#pragma unroll
      for (int rr = 0; rr < 2; ++rr){
        if (lane == 0){
          int r = b * 8 + wv * 2 + rr;
          float v = tanhf(sfus[rr] + bfus_r[rr] + mw0 * dimg_r[rr] + mw1 * dq_r[rr]);
          astore64(&A.tfs[r], tagpack(want, v));
        }
      }
    }

    // PH3: poll fs -> fsl, gates, cell
    {
      u64 w4[4];
#pragma unroll
      for (int k = 0; k < 4; ++k) w4[k] = aload64(&A.tfs[tid + (k << 8)]);
#pragma unroll
      for (int k = 0; k < 4; ++k){
        while ((u32)(w4[k] >> 32) != want) w4[k] = aload64(&A.tfs[tid + (k << 8)]);
        fsl[tid + (k << 8)] = __uint_as_float((u32)w4[k]);
      }
    }
    __syncthreads();
#pragma unroll
    for (int rr = 0; rr < 8; ++rr){
      int lr = wv * 8 + rr;
      int gr = (lr >> 3) * 1024 + b * 8 + (lr & 7);
      float s = dot1024(A.Wid_bf + (size_t)gr * 1024, fsl, lane)
              + dot1024(A.Whd_bf + (size_t)gr * 1024, hl, lane);
      s = wred_sum(s);
      if (lane == 0) gb[lr] = s + A.b_dec[gr];
    }
    __syncthreads();
    if (tid < 8){
      float gi = gb[tid], gf = gb[8 + tid], gg = gb[16 + tid], go = gb[24 + tid];
      float c = sigm(gf) * cdec[tid] + sigm(gi) * tanhf(gg);
      cdec[tid] = c;
      float h = sigm(go) * tanhf(c);
      astore64(&A.thdec[b * 8 + tid], tagpack(want, h));
    }
    // end of iter: poll h_{t+1} -> hl
    {
      u64 w4[4];
#pragma unroll
      for (int k = 0; k < 4; ++k) w4[k] = aload64(&A.thdec[tid + (k << 8)]);
#pragma unroll
      for (int k = 0; k < 4; ++k){
        while ((u32)(w4[k] >> 32) != want) w4[k] = aload64(&A.thdec[tid + (k << 8)]);
        hl[tid + (k << 8)] = __uint_as_float((u32)w4[k]);
      }
    }
    __syncthreads();
  }

  // final logits (h_T)
  {
    int gw = b * 4 + wv;
    for (int r = gw; r < 32000; r += 512){
      float s = dot1024(A.Wfin_bf + (size_t)r * 1024, hl, lane);
      s = wred_sum(s);
      if (lane == 0) A.out[(size_t)(A.T - 1) * 32000 + r] = s + A.bfin[r];
    }
  }
}

// ---------------------------------------------------------------- host
extern "C" void kernel_launch(void* const* d_in, const int* in_sizes, int n_in,
                              void* d_out, int out_size, void* d_ws, size_t ws_size,
                              hipStream_t stream)
{
  const float* img_feats = (const float*)d_in[0];
  const float* q_feats   = (const float*)d_in[1];
  const float* Wi_imgf = (const float*)d_in[2];
  const float* Wh_imgf = (const float*)d_in[3];
  const float* b_imgf  = (const float*)d_in[4];
  const float* Wi_imgb = (const float*)d_in[5];
  const float* Wh_imgb = (const float*)d_in[6];
  const float* b_imgb  = (const float*)d_in[7];
  const float* Wi_qf = (const float*)d_in[8];
  const float* Wh_qf = (const float*)d_in[9];
  const float* b_qf  = (const float*)d_in[10];
  const float* Wi_qb = (const float*)d_in[11];
  const float* Wh_qb = (const float*)d_in[12];
  const float* b_qb  = (const float*)d_in[13];
  const float* Wimg_e = (const float*)d_in[15];
  const float* bimg   = (const float*)d_in[16];
  const float* Wq_e   = (const float*)d_in[18];
  const float* bq     = (const float*)d_in[19];
  const float* Wmod   = (const float*)d_in[20];
  const float* bmod   = (const float*)d_in[21];
  const float* Wmod_img = (const float*)d_in[22];
  const float* Wmod_q   = (const float*)d_in[23];
  const float* Wfus_img = (const float*)d_in[24];
  const float* Wfus_q   = (const float*)d_in[25];
  const float* Wfus     = (const float*)d_in[26];
  const float* bfus     = (const float*)d_in[27];
  const float* Wi_dec = (const float*)d_in[28];
  const float* Wh_dec = (const float*)d_in[29];
  const float* b_dec  = (const float*)d_in[30];
  const float* Wfin = (const float*)d_in[31];
  const float* bfin = (const float*)d_in[32];
  const int T = out_size / 32000;

  char* ws = (char*)d_ws;
  size_t off = 0;
  auto alloc = [&](size_t bytes){ size_t o = off; off += (bytes + 255) & ~(size_t)255; return o; };
  const size_t oA    = alloc(1024ull * 2048 * 2);
  const size_t oWiF  = alloc(2048ull * 2048 * 2);
  const size_t oWiB  = alloc(2048ull * 2048 * 2);
  const size_t oWfin = alloc(32000ull * 1024 * 2);
  const size_t oWfu  = alloc(1024ull * 1024 * 2);
  const size_t oWfI  = alloc(1024ull * 1024 * 2);
  const size_t oWfQ  = alloc(1024ull * 1024 * 2);
  const size_t oWid  = alloc(4096ull * 1024 * 2);
  const size_t oWhd  = alloc(4096ull * 1024 * 2);
  const size_t oxpF  = alloc(1024ull * 2048 * 4);
  const size_t oxpB  = alloc(1024ull * 2048 * 4);
  const size_t oxpQF = alloc(32ull * 2048 * 4);
  const size_t oxpQB = alloc(32ull * 2048 * 4);
  const size_t oemb  = alloc(1024ull * 1024 * 4);
  const size_t oembT = alloc(1024ull * 1024 * 4);
  const size_t oqemb = alloc(32ull * 1024 * 4);
  const size_t oqembT= alloc(1024ull * 32 * 4);
  const size_t oeimg = alloc(1024 * 4);
  const size_t omimg = alloc(1024 * 4);
  const size_t oeq   = alloc(32 * 4);
  const size_t omq   = alloc(32 * 4);
  const size_t oaimg = alloc(1024 * 4);
  const size_t oaq   = alloc(32 * 4);
  const size_t octxi = alloc(1024 * 4);
  const size_t octxq = alloc(1024 * 4);
  const size_t odimg = alloc(1024 * 4);
  const size_t odq   = alloc(1024 * 4);
  const size_t oCTRL = off;
  const size_t ohcomm = alloc(4ull * 2 * 512 * 8);
  const size_t otscal = alloc(2 * 8);
  const size_t otfs   = alloc(1024 * 8);
  const size_t othdec = alloc(1024 * 8);
  const size_t odst   = alloc(128 * 4);
  const size_t oscal  = alloc(64 * 4);
  const size_t ctrlBytes = off - oCTRL;
  (void)ws_size; (void)n_in; (void)in_sizes;

  hipMemsetAsync(ws + oCTRL, 0, ctrlBytes, stream);

  auto cvt = [&](const float* s, size_t o, long n){
    int n4 = (int)(n >> 2);
    int g = (n4 + 255) / 256; if (g > 2048) g = 2048;
    k_cvt<<<dim3(g), dim3(256), 0, stream>>>(s, (u16*)(ws + o), n4);
  };
  cvt(img_feats, oA, 1024L * 2048);
  cvt(Wi_imgf, oWiF, 2048L * 2048);
  cvt(Wi_imgb, oWiB, 2048L * 2048);
  cvt(Wfin, oWfin, 32000L * 1024);
  cvt(Wfus, oWfu, 1024L * 1024);
  cvt(Wfus_img, oWfI, 1024L * 1024);
  cvt(Wfus_q, oWfQ, 1024L * 1024);
  cvt(Wi_dec, oWid, 4096L * 1024);
  cvt(Wh_dec, oWhd, 4096L * 1024);

  k_gemm_xp<<<dim3(16, 8, 2), dim3(256), 0, stream>>>(
      (const u16*)(ws + oA), (const u16*)(ws + oWiF), (const u16*)(ws + oWiB),
      b_imgf, b_imgb, (float*)(ws + oxpF), (float*)(ws + oxpB));

  k_qxp<<<dim3(32, 2), dim3(256), 0, stream>>>(
      q_feats, Wi_qf, Wi_qb, b_qf, b_qb,
      (float*)(ws + oxpQF), (float*)(ws + oxpQB));

  k_scan<<<dim3(128), dim3(256), 0, stream>>>(
      Wh_imgf, Wh_imgb, Wh_qf, Wh_qb,
      (const float*)(ws + oxpF), (const float*)(ws + oxpB),
      (const float*)(ws + oxpQF), (const float*)(ws + oxpQB),
      (float*)(ws + oemb), (float*)(ws + oembT),
      (float*)(ws + oqemb), (float*)(ws + oqembT),
      (u64*)(ws + ohcomm));

  DecArgs DA;
  DA.emb = (const float*)(ws + oemb); DA.embT = (const float*)(ws + oembT);
  DA.qemb = (const float*)(ws + oqemb); DA.qembT = (const float*)(ws + oqembT);
  DA.Wimg_e = Wimg_e; DA.bimg = bimg; DA.Wmod_img = Wmod_img;
  DA.Wq_e = Wq_e; DA.bq = bq; DA.Wmod_q = Wmod_q;
  DA.Wmod = Wmod; DA.bmod = bmod;
  DA.Wfus_bf = (const u16*)(ws + oWfu); DA.bfus = bfus;
  DA.WfusI_bf = (const u16*)(ws + oWfI); DA.WfusQ_bf = (const u16*)(ws + oWfQ);
  DA.Wid_bf = (const u16*)(ws + oWid); DA.Whd_bf = (const u16*)(ws + oWhd); DA.b_dec = b_dec;
  DA.Wfin_bf = (const u16*)(ws + oWfin); DA.bfin = bfin;
  DA.e_img = (float*)(ws + oeimg); DA.m_img = (float*)(ws + omimg);
  DA.e_q = (float*)(ws + oeq); DA.m_q = (float*)(ws + omq);
  DA.a_img = (float*)(ws + oaimg); DA.a_q = (float*)(ws + oaq);
  DA.ctx_img = (float*)(ws + octxi); DA.ctx_q = (float*)(ws + octxq);
  DA.d_img = (float*)(ws + odimg); DA.d_q = (float*)(ws + odq);
  DA.scal = (float*)(ws + oscal);
  DA.tscal = (u64*)(ws + otscal); DA.tfs = (u64*)(ws + otfs); DA.thdec = (u64*)(ws + othdec);
  DA.st = (int*)(ws + odst);
  DA.out = (float*)d_out; DA.T = T;

  k_dec<<<dim3(DG), dim3(256), 0, stream>>>(DA);
}